// Round 1
// baseline (93.431 us; speedup 1.0000x reference)
//
#include <hip/hip_runtime.h>
#include <math.h>

#define C 128
#define RANK 64
#define NB 8192
#define BATCH 2
#define GSTRIDE (C * C + C)  // 16512 floats per (b,chunk) partial: G + colsum

typedef float f32x4 __attribute__((ext_vector_type(4)));
typedef float f32x2 __attribute__((ext_vector_type(2)));

__device__ __forceinline__ float gelu_erf(float y) {
  return 0.5f * y * (1.0f + erff(y * 0.70710678118654752440f));
}

// ---------------------------------------------------------------------------
// Kernel 1: partial Gram G[c][k] = sum_rows x[n][c]*x[n][k] over a row chunk,
// plus partial column sums. Deterministic (no atomics): each (b,chunk) block
// writes its own 16512-float slab.
// ---------------------------------------------------------------------------
__global__ __launch_bounds__(256) void k_gram(const float* __restrict__ x,
                                              float* __restrict__ part,
                                              int nchunk) {
  __shared__ float xs[32][132];  // +4 pad: conflict-free staging writes
  const int chunk = blockIdx.x, b = blockIdx.y;
  const int rpc = NB / nchunk;
  const float* xb = x + ((size_t)(b * NB + chunk * rpc)) * C;
  const int tid = threadIdx.x;
  const int ty = tid >> 4, tx = tid & 15;  // 16x16 threads, 8x8 tile each
  float acc[8][8];
#pragma unroll
  for (int i = 0; i < 8; ++i)
#pragma unroll
    for (int j = 0; j < 8; ++j) acc[i][j] = 0.f;
  float cs = 0.f;
  const int stages = rpc >> 5;
  for (int s = 0; s < stages; ++s) {
    const float* xg = xb + (size_t)s * 32 * C;
#pragma unroll
    for (int it = 0; it < 4; ++it) {
      int idx4 = it * 256 + tid;           // 1024 float4s = 32 rows x 128
      int row = idx4 >> 5;
      int c4 = (idx4 & 31) << 2;
      *reinterpret_cast<f32x4*>(&xs[row][c4]) =
          *reinterpret_cast<const f32x4*>(xg + row * C + c4);
    }
    __syncthreads();
#pragma unroll 4
    for (int row = 0; row < 32; ++row) {
      f32x4 a0 = *reinterpret_cast<const f32x4*>(&xs[row][ty * 8]);
      f32x4 a1 = *reinterpret_cast<const f32x4*>(&xs[row][ty * 8 + 4]);
      f32x4 b0 = *reinterpret_cast<const f32x4*>(&xs[row][tx * 8]);
      f32x4 b1 = *reinterpret_cast<const f32x4*>(&xs[row][tx * 8 + 4]);
#pragma unroll
      for (int i = 0; i < 4; ++i)
#pragma unroll
        for (int j = 0; j < 4; ++j) {
          acc[i][j]         += a0[i] * b0[j];
          acc[i][j + 4]     += a0[i] * b1[j];
          acc[i + 4][j]     += a1[i] * b0[j];
          acc[i + 4][j + 4] += a1[i] * b1[j];
        }
    }
    if (tid < C) {
#pragma unroll
      for (int row = 0; row < 32; ++row) cs += xs[row][tid];
    }
    __syncthreads();
  }
  float* p = part + (size_t)(b * nchunk + chunk) * GSTRIDE;
#pragma unroll
  for (int i = 0; i < 8; ++i) {
    int c = ty * 8 + i;
    f32x4 v0, v1;
#pragma unroll
    for (int j = 0; j < 4; ++j) { v0[j] = acc[i][j]; v1[j] = acc[i][j + 4]; }
    *reinterpret_cast<f32x4*>(&p[c * C + tx * 8]) = v0;
    *reinterpret_cast<f32x4*>(&p[c * C + tx * 8 + 4]) = v1;
  }
  if (tid < C) p[C * C + tid] = cs;
}

// ---------------------------------------------------------------------------
// Kernel 2: reduce partials -> gsum[b][16512]
// ---------------------------------------------------------------------------
__global__ __launch_bounds__(256) void k_reduce(const float* __restrict__ part,
                                                float* __restrict__ gsum,
                                                int nchunk) {
  int e = blockIdx.x * 256 + threadIdx.x;
  if (e >= BATCH * GSTRIDE) return;
  int b = e / GSTRIDE;
  int i = e - b * GSTRIDE;
  const float* p = part + (size_t)b * nchunk * GSTRIDE + i;
  float s = 0.f;
  for (int ch = 0; ch < nchunk; ++ch) s += p[(size_t)ch * GSTRIDE];
  gsum[e] = s;
}

// ---------------------------------------------------------------------------
// Kernel 3: integral_c[b][r][c] = (sum_k psi_w[k][r*C+c]*G[b][k][c]
//                                  + psi_b[r*C+c]*S[b][c]) / NB
// ---------------------------------------------------------------------------
__global__ __launch_bounds__(128) void k_integral(
    const float* __restrict__ psi_w, const float* __restrict__ psi_b,
    const float* __restrict__ gsum, float* __restrict__ integ) {
  const int r = blockIdx.x, b = blockIdx.y, c = threadIdx.x;
  const float* G = gsum + (size_t)b * GSTRIDE;
  float acc = 0.f;
#pragma unroll 8
  for (int k = 0; k < C; ++k)
    acc += psi_w[(size_t)k * (RANK * C) + r * C + c] * G[k * C + c];
  acc += psi_b[r * C + c] * G[C * C + c];
  integ[(b * RANK + r) * C + c] = acc * (1.0f / NB);
}

// ---------------------------------------------------------------------------
// Kernel 4: fused per-row  phi -> (w_x, kernel_out) -> gelu.
// All weights live in LDS (W 64KB + phi_w 32KB + integ 32KB + x tile + phi tile
// = 155.75KB of 160KB). 32 rows per block, register 4x4 tiles.
// ---------------------------------------------------------------------------
__global__ __launch_bounds__(256) void k_main(
    const float* __restrict__ x, const float* __restrict__ W_w,
    const float* __restrict__ W_b, const float* __restrict__ phi_w,
    const float* __restrict__ phi_b, const float* __restrict__ integ,
    float* __restrict__ out) {
  __shared__ float Wl[C * C];         // [c][j]
  __shared__ float Pl[C * RANK];      // [c][r]
  __shared__ float Il[RANK * C];      // [r][j]
  __shared__ float xsT[C][36];        // [c][row], pad->36 keeps 16B align
  __shared__ float phT[RANK][36];     // [r][row]
  __shared__ float Wbl[C];
  __shared__ float pbl[RANK];
  const int tid = threadIdx.x;
  const int row0 = blockIdx.x * 32;
  const int b = row0 >> 13;  // / 8192
#pragma unroll
  for (int it = 0; it < 16; ++it) {
    int i = it * 1024 + tid * 4;
    *reinterpret_cast<f32x4*>(&Wl[i]) = *reinterpret_cast<const f32x4*>(&W_w[i]);
  }
#pragma unroll
  for (int it = 0; it < 8; ++it) {
    int i = it * 1024 + tid * 4;
    *reinterpret_cast<f32x4*>(&Pl[i]) = *reinterpret_cast<const f32x4*>(&phi_w[i]);
    *reinterpret_cast<f32x4*>(&Il[i]) =
        *reinterpret_cast<const f32x4*>(&integ[b * (RANK * C) + i]);
  }
  if (tid < C) Wbl[tid] = W_b[tid];
  else if (tid < C + RANK) pbl[tid - C] = phi_b[tid - C];
#pragma unroll
  for (int it = 0; it < 16; ++it) {
    int idx = it * 256 + tid;  // 4096 = 32 rows x 128 cols
    int row = idx >> 7, c = idx & 127;
    xsT[c][row] = x[(size_t)(row0 + row) * C + c];
  }
  __syncthreads();
  // ---- phase 1: phi[row][r] for the 32-row tile -> phT (transposed) ----
  {
    const int rowt = tid >> 4;          // 0..15 -> rows 2*rowt, 2*rowt+1
    const int r0 = (tid & 15) * 4;
    float pa[2][4];
#pragma unroll
    for (int q = 0; q < 4; ++q) { pa[0][q] = pbl[r0 + q]; pa[1][q] = pbl[r0 + q]; }
#pragma unroll 4
    for (int c = 0; c < C; ++c) {
      f32x2 xv = *reinterpret_cast<const f32x2*>(&xsT[c][rowt * 2]);
      f32x4 wv = *reinterpret_cast<const f32x4*>(&Pl[c * RANK + r0]);
#pragma unroll
      for (int q = 0; q < 4; ++q) {
        pa[0][q] += xv[0] * wv[q];
        pa[1][q] += xv[1] * wv[q];
      }
    }
#pragma unroll
    for (int q = 0; q < 4; ++q) {
      phT[r0 + q][rowt * 2] = pa[0][q];
      phT[r0 + q][rowt * 2 + 1] = pa[1][q];
    }
  }
  __syncthreads();
  // ---- phase 2+3: w_x + kernel_out + gelu ----
  {
    const int rt = tid >> 5;            // 0..7 -> rows 4*rt..4*rt+3
    const int j0 = (tid & 31) * 4;
    float acc[4][4];
#pragma unroll
    for (int i = 0; i < 4; ++i)
#pragma unroll
      for (int q = 0; q < 4; ++q) acc[i][q] = Wbl[j0 + q];
#pragma unroll 4
    for (int c = 0; c < C; ++c) {
      f32x4 xv = *reinterpret_cast<const f32x4*>(&xsT[c][rt * 4]);
      f32x4 wv = *reinterpret_cast<const f32x4*>(&Wl[c * C + j0]);
#pragma unroll
      for (int i = 0; i < 4; ++i)
#pragma unroll
        for (int q = 0; q < 4; ++q) acc[i][q] += xv[i] * wv[q];
    }
#pragma unroll 4
    for (int r = 0; r < RANK; ++r) {
      f32x4 pv = *reinterpret_cast<const f32x4*>(&phT[r][rt * 4]);
      f32x4 iv = *reinterpret_cast<const f32x4*>(&Il[r * C + j0]);
#pragma unroll
      for (int i = 0; i < 4; ++i)
#pragma unroll
        for (int q = 0; q < 4; ++q) acc[i][q] += pv[i] * iv[q];
    }
#pragma unroll
    for (int i = 0; i < 4; ++i) {
      f32x4 o;
#pragma unroll
      for (int q = 0; q < 4; ++q) o[q] = gelu_erf(acc[i][q]);
      *reinterpret_cast<f32x4*>(&out[(size_t)(row0 + rt * 4 + i) * C + j0]) = o;
    }
  }
}

extern "C" void kernel_launch(void* const* d_in, const int* in_sizes, int n_in,
                              void* d_out, int out_size, void* d_ws, size_t ws_size,
                              hipStream_t stream) {
  const float* x     = (const float*)d_in[0];
  const float* W_w   = (const float*)d_in[1];
  const float* W_b   = (const float*)d_in[2];
  const float* phi_w = (const float*)d_in[3];
  const float* phi_b = (const float*)d_in[4];
  const float* psi_w = (const float*)d_in[5];
  const float* psi_b = (const float*)d_in[6];
  float* out = (float*)d_out;

  // Workspace layout: [gsum: 2*16512][integ: 2*8192][partials: 2*nchunk*16512]
  float* gsum  = (float*)d_ws;
  float* integ = gsum + BATCH * GSTRIDE;
  float* part  = integ + BATCH * RANK * C;
  size_t reserved = ((size_t)BATCH * GSTRIDE + (size_t)BATCH * RANK * C) * 4;
  int nchunk = 1;
  const int cands[8] = {128, 64, 32, 16, 8, 4, 2, 1};
  for (int ci = 0; ci < 8; ++ci) {
    size_t need = reserved + (size_t)BATCH * cands[ci] * GSTRIDE * 4;
    if (need <= ws_size) { nchunk = cands[ci]; break; }
  }

  const int total_rows = in_sizes[0] / C;  // 16384

  k_gram<<<dim3(nchunk, BATCH), 256, 0, stream>>>(x, part, nchunk);
  k_reduce<<<(BATCH * GSTRIDE + 255) / 256, 256, 0, stream>>>(part, gsum, nchunk);
  k_integral<<<dim3(RANK, BATCH), 128, 0, stream>>>(psi_w, psi_b, gsum, integ);
  k_main<<<total_rows / 32, 256, 0, stream>>>(x, W_w, W_b, phi_w, phi_b, integ, out);
}

// Round 2
// 35.792 us; speedup vs baseline: 2.6104x; 2.6104x over previous
//
#include <hip/hip_runtime.h>
#include <math.h>

#define C 128
#define RANK 64
#define NB 8192
#define BATCH 2
#define NCHUNK 128                 // split-K chunks per batch (64 rows each)
#define GSTRIDE (C * C + C)        // per-chunk partial: G[128][128] + colsum[128]

typedef float f32x4 __attribute__((ext_vector_type(4)));
typedef short bf16x8 __attribute__((ext_vector_type(8)));
typedef unsigned short u16x4 __attribute__((ext_vector_type(4)));

__device__ __forceinline__ unsigned short f2b(float f) {
  union { float f; unsigned u; } v; v.f = f;
  unsigned r = v.u + 0x7fffu + ((v.u >> 16) & 1u);   // RNE
  return (unsigned short)(r >> 16);
}
__device__ __forceinline__ float gelu_erf(float y) {
  return 0.5f * y * (1.0f + erff(y * 0.70710678118654752440f));
}
#define MFMA(a, b, c) __builtin_amdgcn_mfma_f32_16x16x32_bf16(a, b, c, 0, 0, 0)

// ---------------------------------------------------------------------------
// k_gram: blocks [0,256): partial Gram via MFMA over a 64-row chunk (bf16),
// plus f32 column sums. Blocks [256,280): pack W_w / phi_w into bf16
// fragment-ordered buffers for k_main.
// Fragment order: elem o = ((nt*KT + kt)*64 + lane)*8 + j holds
//   B[k = kt*32 + (lane>>4)*8 + j][n = nt*16 + (lane&15)].
// ---------------------------------------------------------------------------
__global__ __launch_bounds__(256) void k_gram(
    const float* __restrict__ x, float* __restrict__ part,
    unsigned short* __restrict__ wtf, unsigned short* __restrict__ pwf,
    const float* __restrict__ W_w, const float* __restrict__ phi_w) {
  const int blk = blockIdx.x;
  const int tid = threadIdx.x;
  if (blk >= BATCH * NCHUNK) {
    const int p = blk - BATCH * NCHUNK;
    if (p < 16) {  // W_w -> wtf, 16384 elems, nt 0..7, kt 0..3
      int o0 = p * 1024 + tid * 4;
      u16x4 v;
#pragma unroll
      for (int q = 0; q < 4; ++q) {
        int o = o0 + q;
        int j = o & 7, lane = (o >> 3) & 63, kt = (o >> 9) & 3, nt = o >> 11;
        int n = nt * 16 + (lane & 15);
        int k = kt * 32 + ((lane >> 4) << 3) + j;
        v[q] = f2b(W_w[k * C + n]);
      }
      *(u16x4*)(wtf + o0) = v;
    } else {       // phi_w -> pwf, 8192 elems, nt 0..3 (r-tiles), kt 0..3
      int o0 = (p - 16) * 1024 + tid * 4;
      u16x4 v;
#pragma unroll
      for (int q = 0; q < 4; ++q) {
        int o = o0 + q;
        int j = o & 7, lane = (o >> 3) & 63, kt = (o >> 9) & 3, nt = o >> 11;
        int r = nt * 16 + (lane & 15);
        int c = kt * 32 + ((lane >> 4) << 3) + j;
        v[q] = f2b(phi_w[c * RANK + r]);
      }
      *(u16x4*)(pwf + o0) = v;
    }
    return;
  }
  // ---- Gram over 64 rows ----
  __shared__ short xsT[C * 72];     // x^T tile [c][n], pad 72 (2-way banks = free)
  __shared__ float csp[2][C];
  const int b = blk >> 7, chunk = blk & 127;
  const float* xb = x + ((size_t)(b * NB + chunk * 64)) * C;
  {
    const int c = tid & 127, ng = tid >> 7;
    float cs = 0.f;
#pragma unroll
    for (int it = 0; it < 8; ++it) {
      int n0 = it * 8 + ng * 4;
      u16x4 pv;
#pragma unroll
      for (int q = 0; q < 4; ++q) {
        float v = xb[(size_t)(n0 + q) * C + c];
        cs += v;
        pv[q] = f2b(v);
      }
      *(u16x4*)(&xsT[c * 72 + n0]) = pv;
    }
    csp[ng][c] = cs;
  }
  __syncthreads();
  const int l = tid & 63, w = tid >> 6;
  const int lr = l & 15, lq = l >> 4;
  const int ti0 = w * 2;
  f32x4 acc[2][8];
#pragma unroll
  for (int i = 0; i < 2; ++i)
#pragma unroll
    for (int tj = 0; tj < 8; ++tj) acc[i][tj] = (f32x4)(0.f);
  bf16x8 af[2][2];
#pragma unroll
  for (int i = 0; i < 2; ++i)
#pragma unroll
    for (int kk = 0; kk < 2; ++kk)
      af[i][kk] = *(const bf16x8*)(&xsT[((ti0 + i) * 16 + lr) * 72 + kk * 32 + lq * 8]);
#pragma unroll
  for (int tj = 0; tj < 8; ++tj) {
#pragma unroll
    for (int kk = 0; kk < 2; ++kk) {
      bf16x8 bfr = *(const bf16x8*)(&xsT[(tj * 16 + lr) * 72 + kk * 32 + lq * 8]);
      acc[0][tj] = MFMA(af[0][kk], bfr, acc[0][tj]);
      acc[1][tj] = MFMA(af[1][kk], bfr, acc[1][tj]);
    }
  }
  float* dst = part + (size_t)blk * GSTRIDE;
#pragma unroll
  for (int i = 0; i < 2; ++i)
#pragma unroll
    for (int tj = 0; tj < 8; ++tj)
#pragma unroll
      for (int q = 0; q < 4; ++q) {
        int ci = (ti0 + i) * 16 + lq * 4 + q;
        int cj = tj * 16 + lr;
        dst[ci * C + cj] = acc[i][tj][q];
      }
  if (tid < C) dst[C * C + tid] = csp[0][tid] + csp[1][tid];
}

// ---------------------------------------------------------------------------
// k_reduce: gsum[b][i] = sum over 128 chunk partials
// ---------------------------------------------------------------------------
__global__ __launch_bounds__(256) void k_reduce(const float* __restrict__ part,
                                                float* __restrict__ gsum) {
  int e = blockIdx.x * 256 + threadIdx.x;
  if (e >= BATCH * GSTRIDE) return;
  int b = e / GSTRIDE;
  int i = e - b * GSTRIDE;
  const float* p = part + (size_t)b * NCHUNK * GSTRIDE + i;
  float s = 0.f;
#pragma unroll 8
  for (int ch = 0; ch < NCHUNK; ++ch) s += p[(size_t)ch * GSTRIDE];
  gsum[e] = s;
}

// ---------------------------------------------------------------------------
// k_integral: integ[b][r][c] = (sum_k psiw[k][r*C+c]*G[b][k][c]
//                               + psib[r*C+c]*S[b][c]) / NB
// written directly in bf16 fragment order (B-operand of T3), kt 0..1.
// ---------------------------------------------------------------------------
__global__ __launch_bounds__(128) void k_integral(
    const float* __restrict__ psi_w, const float* __restrict__ psi_b,
    const float* __restrict__ gsum, unsigned short* __restrict__ itf) {
  const int r = blockIdx.x, b = blockIdx.y, c = threadIdx.x;
  const float* G = gsum + (size_t)b * GSTRIDE;
  float acc = 0.f;
#pragma unroll 8
  for (int k = 0; k < C; ++k)
    acc += psi_w[(size_t)k * (RANK * C) + r * C + c] * G[k * C + c];
  acc += psi_b[r * C + c] * G[C * C + c];
  acc *= (1.0f / NB);
  int nt = c >> 4, kt = r >> 5;
  int lane = ((r >> 3) & 3) * 16 + (c & 15), j = r & 7;
  itf[(size_t)((((b * 8 + nt) * 2 + kt) * 64 + lane)) * 8 + j] = f2b(acc);
}

// ---------------------------------------------------------------------------
// k_main: 64 rows/block, 512 threads (8 waves as 2m x 4n), MFMA fused
//   T1 phi = x*phi_w + phi_b        (K=128, N=64)
//   T2 acc = x*W_w + W_b            (K=128, N=128)
//   T3 acc += phi_bf16 * integ      (K=64,  N=128)
//   out = gelu_erf(acc)
// Weight B-fragments preloaded coalesced from fragment-ordered buffers.
// ---------------------------------------------------------------------------
__global__ __launch_bounds__(512, 2) void k_main(
    const float* __restrict__ x, const float* __restrict__ W_b,
    const float* __restrict__ phi_b, const unsigned short* __restrict__ wtf,
    const unsigned short* __restrict__ pwf, const unsigned short* __restrict__ itf,
    float* __restrict__ out) {
  __shared__ short xs[64 * 136];    // x tile bf16, row-major, pad 136
  __shared__ short phT[64 * 72];    // phi tile bf16, row-major, pad 72
  const int tid = threadIdx.x, l = tid & 63, w = tid >> 6;
  const int wm = w >> 2, wn = w & 3;
  const int row0 = blockIdx.x * 64;
  const int b = blockIdx.x >> 7;
  const int lr = l & 15, lq = l >> 4;
  // preload weight fragments (coalesced 16B/lane)
  bf16x8 wb[2][4], pw[4], itb[2][2];
  const bf16x8* WF = (const bf16x8*)wtf;
  const bf16x8* PF = (const bf16x8*)pwf;
  const bf16x8* IF = (const bf16x8*)itf;
#pragma unroll
  for (int j = 0; j < 2; ++j)
#pragma unroll
    for (int kt = 0; kt < 4; ++kt)
      wb[j][kt] = WF[((wn * 2 + j) * 4 + kt) * 64 + l];
#pragma unroll
  for (int kt = 0; kt < 4; ++kt) pw[kt] = PF[(wn * 4 + kt) * 64 + l];
#pragma unroll
  for (int j = 0; j < 2; ++j)
#pragma unroll
    for (int kt = 0; kt < 2; ++kt)
      itb[j][kt] = IF[((b * 8 + wn * 2 + j) * 2 + kt) * 64 + l];
  // stage x tile (f32 -> bf16)
#pragma unroll
  for (int s = 0; s < 2; ++s) {
    int ch = tid + s * 512;                 // 1024 chunks of 8
    int row = ch >> 4, c8 = (ch & 15) * 8;
    const float* src = x + (size_t)(row0 + row) * C + c8;
    f32x4 v0 = *(const f32x4*)src;
    f32x4 v1 = *(const f32x4*)(src + 4);
    bf16x8 pv;
#pragma unroll
    for (int q = 0; q < 4; ++q) { pv[q] = (short)f2b(v0[q]); pv[q + 4] = (short)f2b(v1[q]); }
    *(bf16x8*)(&xs[row * 136 + c8]) = pv;
  }
  // accumulator init with biases
  float wb0 = W_b[wn * 32 + lr], wb1 = W_b[wn * 32 + 16 + lr];
  float pb0 = phi_b[wn * 16 + lr];
  f32x4 acc[2][2], pacc[2];
#pragma unroll
  for (int i = 0; i < 2; ++i) {
    acc[i][0] = (f32x4)(wb0);
    acc[i][1] = (f32x4)(wb1);
    pacc[i] = (f32x4)(pb0);
  }
  __syncthreads();
  // T1 + T2
#pragma unroll
  for (int kt = 0; kt < 4; ++kt) {
    bf16x8 a0 = *(const bf16x8*)(&xs[(wm * 32 + lr) * 136 + kt * 32 + lq * 8]);
    bf16x8 a1 = *(const bf16x8*)(&xs[(wm * 32 + 16 + lr) * 136 + kt * 32 + lq * 8]);
    pacc[0] = MFMA(a0, pw[kt], pacc[0]);
    pacc[1] = MFMA(a1, pw[kt], pacc[1]);
    acc[0][0] = MFMA(a0, wb[0][kt], acc[0][0]);
    acc[0][1] = MFMA(a0, wb[1][kt], acc[0][1]);
    acc[1][0] = MFMA(a1, wb[0][kt], acc[1][0]);
    acc[1][1] = MFMA(a1, wb[1][kt], acc[1][1]);
  }
  // phi -> bf16 -> LDS
#pragma unroll
  for (int i = 0; i < 2; ++i)
#pragma unroll
    for (int q = 0; q < 4; ++q) {
      int row = wm * 32 + i * 16 + lq * 4 + q;
      phT[row * 72 + wn * 16 + lr] = (short)f2b(pacc[i][q]);
    }
  __syncthreads();
  // T3
#pragma unroll
  for (int kt = 0; kt < 2; ++kt) {
    bf16x8 p0 = *(const bf16x8*)(&phT[(wm * 32 + lr) * 72 + kt * 32 + lq * 8]);
    bf16x8 p1 = *(const bf16x8*)(&phT[(wm * 32 + 16 + lr) * 72 + kt * 32 + lq * 8]);
    acc[0][0] = MFMA(p0, itb[0][kt], acc[0][0]);
    acc[0][1] = MFMA(p0, itb[1][kt], acc[0][1]);
    acc[1][0] = MFMA(p1, itb[0][kt], acc[1][0]);
    acc[1][1] = MFMA(p1, itb[1][kt], acc[1][1]);
  }
  // epilogue: exact-erf gelu, store (16 lanes = 64B contiguous per store)
#pragma unroll
  for (int i = 0; i < 2; ++i)
#pragma unroll
    for (int j = 0; j < 2; ++j)
#pragma unroll
      for (int q = 0; q < 4; ++q) {
        int row = row0 + wm * 32 + i * 16 + lq * 4 + q;
        int col = wn * 32 + j * 16 + lr;
        out[(size_t)row * C + col] = gelu_erf(acc[i][j][q]);
      }
}

extern "C" void kernel_launch(void* const* d_in, const int* in_sizes, int n_in,
                              void* d_out, int out_size, void* d_ws, size_t ws_size,
                              hipStream_t stream) {
  const float* x     = (const float*)d_in[0];
  const float* W_w   = (const float*)d_in[1];
  const float* W_b   = (const float*)d_in[2];
  const float* phi_w = (const float*)d_in[3];
  const float* phi_b = (const float*)d_in[4];
  const float* psi_w = (const float*)d_in[5];
  const float* psi_b = (const float*)d_in[6];
  float* out = (float*)d_out;

  // ws layout: part[256*16512 f32] | gsum[2*16512 f32] | wtf[16384 bf16]
  //            | pwf[8192 bf16] | itf[16384 bf16]   (~16.3 MiB total)
  float* part = (float*)d_ws;
  float* gsum = part + (size_t)BATCH * NCHUNK * GSTRIDE;
  unsigned short* wtf = (unsigned short*)(gsum + BATCH * GSTRIDE);
  unsigned short* pwf = wtf + 16384;
  unsigned short* itf = pwf + 8192;

  k_gram<<<BATCH * NCHUNK + 24, 256, 0, stream>>>(x, part, wtf, pwf, W_w, phi_w);
  k_reduce<<<(BATCH * GSTRIDE + 255) / 256, 256, 0, stream>>>(part, gsum);
  k_integral<<<dim3(RANK, BATCH), 128, 0, stream>>>(psi_w, psi_b, gsum, itf);
  k_main<<<(BATCH * NB) / 64, 512, 0, stream>>>(x, W_b, phi_b, wtf, pwf, itf, out);
}

// Round 3
// 29.114 us; speedup vs baseline: 3.2091x; 1.2294x over previous
//
#include <hip/hip_runtime.h>
#include <math.h>

#define C 128
#define RANK 64
#define NB 8192
#define BATCH 2
#define NCHUNK 128                 // 64-row chunks per batch

typedef float f32x4 __attribute__((ext_vector_type(4)));
typedef short bf16x8 __attribute__((ext_vector_type(8)));
typedef unsigned short u16x4 __attribute__((ext_vector_type(4)));

__device__ __forceinline__ unsigned short f2b(float f) {
  union { float f; unsigned u; } v; v.f = f;
  unsigned r = v.u + 0x7fffu + ((v.u >> 16) & 1u);   // RNE
  return (unsigned short)(r >> 16);
}
__device__ __forceinline__ float b2f(unsigned short h) {
  union { unsigned u; float f; } v; v.u = ((unsigned)h) << 16;
  return v.f;
}
__device__ __forceinline__ float gelu_erf(float y) {
  return 0.5f * y * (1.0f + erff(y * 0.70710678118654752440f));
}
#define MFMA(a, b, c) __builtin_amdgcn_mfma_f32_16x16x32_bf16(a, b, c, 0, 0, 0)

// ---------------------------------------------------------------------------
// k_gram: blocks [0,256): 64-row Gram partial via MFMA (8 waves), bf16 store,
// f32 column-sum partial. Blocks [256,268): pack W_w / phi_w to fragment order.
// Fragment order: o = ((nt*KT+kt)*64 + lane)*8 + j  holds
//   B[k = kt*32 + (lane>>4)*8 + j][n = nt*16 + (lane&15)].
// ---------------------------------------------------------------------------
__global__ __launch_bounds__(512) void k_gram(
    const float* __restrict__ x, unsigned short* __restrict__ partG,
    float* __restrict__ partS,
    unsigned short* __restrict__ wtf, unsigned short* __restrict__ pwf,
    const float* __restrict__ W_w, const float* __restrict__ phi_w) {
  const int blk = blockIdx.x;
  const int tid = threadIdx.x;
  if (blk >= BATCH * NCHUNK) {
    const int p = blk - BATCH * NCHUNK;
    if (p < 8) {   // W_w -> wtf, 16384 elems
      int o0 = p * 2048 + tid * 4;
      u16x4 v;
#pragma unroll
      for (int q = 0; q < 4; ++q) {
        int o = o0 + q;
        int j = o & 7, lane = (o >> 3) & 63, kt = (o >> 9) & 3, nt = o >> 11;
        int n = nt * 16 + (lane & 15);
        int k = kt * 32 + ((lane >> 4) << 3) + j;
        v[q] = f2b(W_w[k * C + n]);
      }
      *(u16x4*)(wtf + o0) = v;
    } else {       // phi_w -> pwf, 8192 elems
      int o0 = (p - 8) * 2048 + tid * 4;
      u16x4 v;
#pragma unroll
      for (int q = 0; q < 4; ++q) {
        int o = o0 + q;
        int j = o & 7, lane = (o >> 3) & 63, kt = (o >> 9) & 3, nt = o >> 11;
        int r = nt * 16 + (lane & 15);
        int c = kt * 32 + ((lane >> 4) << 3) + j;
        v[q] = f2b(phi_w[c * RANK + r]);
      }
      *(u16x4*)(pwf + o0) = v;
    }
    return;
  }
  __shared__ short xsT[C * 76];     // [c][n], stride 76: aligned + conflict-free
  __shared__ float csp[4][C];
  const int b = blk >> 7, chunk = blk & 127;
  const float* xb = x + ((size_t)(b * NB + chunk * 64)) * C;
  {
    const int c = tid & 127, ng = tid >> 7;   // ng 0..3
    float cs = 0.f;
#pragma unroll
    for (int it = 0; it < 4; ++it) {
      int n0 = it * 16 + ng * 4;
      u16x4 pv;
#pragma unroll
      for (int q = 0; q < 4; ++q) {
        float v = xb[(size_t)(n0 + q) * C + c];
        cs += v;
        pv[q] = f2b(v);
      }
      *(u16x4*)(&xsT[c * 76 + n0]) = pv;
    }
    csp[ng][c] = cs;
  }
  __syncthreads();
  const int l = tid & 63, w = tid >> 6;       // 8 waves, wave = row-tile
  const int lr = l & 15, lq = l >> 4;
  f32x4 acc[8];
#pragma unroll
  for (int tj = 0; tj < 8; ++tj) acc[tj] = (f32x4)(0.f);
  bf16x8 af[2];
#pragma unroll
  for (int kk = 0; kk < 2; ++kk)
    af[kk] = *(const bf16x8*)(&xsT[(w * 16 + lr) * 76 + kk * 32 + lq * 8]);
#pragma unroll
  for (int tj = 0; tj < 8; ++tj) {
#pragma unroll
    for (int kk = 0; kk < 2; ++kk) {
      bf16x8 bfr = *(const bf16x8*)(&xsT[(tj * 16 + lr) * 76 + kk * 32 + lq * 8]);
      acc[tj] = MFMA(af[kk], bfr, acc[tj]);
    }
  }
  unsigned short* dst = partG + (size_t)blk * (C * C);
#pragma unroll
  for (int tj = 0; tj < 8; ++tj)
#pragma unroll
    for (int q = 0; q < 4; ++q) {
      int ci = w * 16 + lq * 4 + q;
      int cj = tj * 16 + lr;
      dst[ci * C + cj] = f2b(acc[tj][q]);
    }
  if (tid < C)
    partS[blk * C + tid] = csp[0][tid] + csp[1][tid] + csp[2][tid] + csp[3][tid];
}

// ---------------------------------------------------------------------------
// k_reduce: gsumG[b][i] = sum_ch b2f(partG), gsumS[b][c] = sum_ch partS
// ---------------------------------------------------------------------------
__global__ __launch_bounds__(512) void k_reduce(
    const unsigned short* __restrict__ partG, const float* __restrict__ partS,
    float* __restrict__ gsumG, float* __restrict__ gsumS) {
  int e = blockIdx.x * 512 + threadIdx.x;
  if (e < BATCH * C * C) {
    int b = e >> 14, i = e & (C * C - 1);
    const unsigned short* p = partG + (size_t)b * NCHUNK * (C * C) + i;
    float s = 0.f;
#pragma unroll 8
    for (int ch = 0; ch < NCHUNK; ++ch) s += b2f(p[(size_t)ch * (C * C)]);
    gsumG[e] = s;
  } else if (e < BATCH * C * C + BATCH * C) {
    int idx = e - BATCH * C * C;
    int b = idx >> 7, c = idx & 127;
    const float* p = partS + (size_t)b * NCHUNK * C + c;
    float s = 0.f;
#pragma unroll 8
    for (int ch = 0; ch < NCHUNK; ++ch) s += p[(size_t)ch * C];
    gsumS[idx] = s;
  }
}

// ---------------------------------------------------------------------------
// k_integral: integ[b][r][c] = (sum_k psiw[k][r*C+c]*G[b][k][c]
//                               + psib[r*C+c]*S[b][c]) / NB -> itf (bf16 frag)
// grid (r=64, ch=4), 256 threads = kg(8) x c32(32); both batches per thread.
// ---------------------------------------------------------------------------
__global__ __launch_bounds__(256) void k_integral(
    const float* __restrict__ psi_w, const float* __restrict__ psi_b,
    const float* __restrict__ gsumG, const float* __restrict__ gsumS,
    unsigned short* __restrict__ itf) {
  __shared__ float red[2][8][32];
  const int r = blockIdx.x, ch = blockIdx.y;
  const int tid = threadIdx.x, kg = tid >> 5, c32 = tid & 31;
  const int c = ch * 32 + c32;
  const float* psW = psi_w + (size_t)r * C + c;
  const float* G0 = gsumG + c;
  const float* G1 = gsumG + C * C + c;
  float a0 = 0.f, a1 = 0.f;
#pragma unroll
  for (int i = 0; i < 16; ++i) {
    int k = kg * 16 + i;
    float pw = psW[(size_t)k * (RANK * C)];
    a0 += pw * G0[k * C];
    a1 += pw * G1[k * C];
  }
  red[0][kg][c32] = a0;
  red[1][kg][c32] = a1;
  __syncthreads();
  if (tid < 64) {
    int b = tid >> 5, cc = tid & 31;
    float s = 0.f;
#pragma unroll
    for (int g = 0; g < 8; ++g) s += red[b][g][cc];
    int cg = ch * 32 + cc;
    s += psi_b[r * C + cg] * gsumS[b * C + cg];
    s *= (1.0f / NB);
    int nt = cg >> 4, kt = r >> 5;
    int lane = ((r >> 3) & 3) * 16 + (cg & 15), j = r & 7;
    itf[(size_t)(((b * 8 + nt) * 2 + kt) * 64 + lane) * 8 + j] = f2b(s);
  }
}

// ---------------------------------------------------------------------------
// k_main: 32 rows/block, 256 threads (4 waves = 4 col-tiles), MFMA fused
//   T1 phi = x*phi_w + phi_b ; T2 acc = x*W_w + W_b ; T3 acc += phi*integ
//   out = gelu_erf(acc)
// ---------------------------------------------------------------------------
__global__ __launch_bounds__(256, 2) void k_main(
    const float* __restrict__ x, const float* __restrict__ W_b,
    const float* __restrict__ phi_b, const unsigned short* __restrict__ wtf,
    const unsigned short* __restrict__ pwf, const unsigned short* __restrict__ itf,
    float* __restrict__ out) {
  __shared__ short xs[32 * 136];
  __shared__ short phT[32 * 72];
  const int tid = threadIdx.x, l = tid & 63, wn = tid >> 6;
  const int row0 = blockIdx.x * 32;
  const int b = blockIdx.x >> 8;
  const int lr = l & 15, lq = l >> 4;
  bf16x8 wb[2][4], pw[4], itb[2][2];
  const bf16x8* WF = (const bf16x8*)wtf;
  const bf16x8* PF = (const bf16x8*)pwf;
  const bf16x8* IF = (const bf16x8*)itf;
#pragma unroll
  for (int j = 0; j < 2; ++j)
#pragma unroll
    for (int kt = 0; kt < 4; ++kt)
      wb[j][kt] = WF[((wn * 2 + j) * 4 + kt) * 64 + l];
#pragma unroll
  for (int kt = 0; kt < 4; ++kt) pw[kt] = PF[(wn * 4 + kt) * 64 + l];
#pragma unroll
  for (int j = 0; j < 2; ++j)
#pragma unroll
    for (int kt = 0; kt < 2; ++kt)
      itb[j][kt] = IF[((b * 8 + wn * 2 + j) * 2 + kt) * 64 + l];
  // stage x tile (f32 -> bf16): 512 chunks of 8, 2 per thread
#pragma unroll
  for (int s = 0; s < 2; ++s) {
    int ch = tid + s * 256;
    int row = ch >> 4, c8 = (ch & 15) * 8;
    const float* src = x + (size_t)(row0 + row) * C + c8;
    f32x4 v0 = *(const f32x4*)src;
    f32x4 v1 = *(const f32x4*)(src + 4);
    bf16x8 pv;
#pragma unroll
    for (int q = 0; q < 4; ++q) { pv[q] = (short)f2b(v0[q]); pv[q + 4] = (short)f2b(v1[q]); }
    *(bf16x8*)(&xs[row * 136 + c8]) = pv;
  }
  float wb0 = W_b[wn * 32 + lr], wb1 = W_b[wn * 32 + 16 + lr];
  float pb0 = phi_b[wn * 16 + lr];
  f32x4 acc[2][2], pacc[2];
#pragma unroll
  for (int i = 0; i < 2; ++i) {
    acc[i][0] = (f32x4)(wb0);
    acc[i][1] = (f32x4)(wb1);
    pacc[i] = (f32x4)(pb0);
  }
  __syncthreads();
#pragma unroll
  for (int kt = 0; kt < 4; ++kt) {
    bf16x8 a0 = *(const bf16x8*)(&xs[lr * 136 + kt * 32 + lq * 8]);
    bf16x8 a1 = *(const bf16x8*)(&xs[(16 + lr) * 136 + kt * 32 + lq * 8]);
    pacc[0] = MFMA(a0, pw[kt], pacc[0]);
    pacc[1] = MFMA(a1, pw[kt], pacc[1]);
    acc[0][0] = MFMA(a0, wb[0][kt], acc[0][0]);
    acc[0][1] = MFMA(a0, wb[1][kt], acc[0][1]);
    acc[1][0] = MFMA(a1, wb[0][kt], acc[1][0]);
    acc[1][1] = MFMA(a1, wb[1][kt], acc[1][1]);
  }
#pragma unroll
  for (int i = 0; i < 2; ++i)
#pragma unroll
    for (int q = 0; q < 4; ++q) {
      int row = i * 16 + lq * 4 + q;
      phT[row * 72 + wn * 16 + lr] = (short)f2b(pacc[i][q]);
    }
  __syncthreads();
#pragma unroll
  for (int kt = 0; kt < 2; ++kt) {
    bf16x8 p0 = *(const bf16x8*)(&phT[lr * 72 + kt * 32 + lq * 8]);
    bf16x8 p1 = *(const bf16x8*)(&phT[(16 + lr) * 72 + kt * 32 + lq * 8]);
    acc[0][0] = MFMA(p0, itb[0][kt], acc[0][0]);
    acc[0][1] = MFMA(p0, itb[1][kt], acc[0][1]);
    acc[1][0] = MFMA(p1, itb[0][kt], acc[1][0]);
    acc[1][1] = MFMA(p1, itb[1][kt], acc[1][1]);
  }
#pragma unroll
  for (int i = 0; i < 2; ++i)
#pragma unroll
    for (int j = 0; j < 2; ++j)
#pragma unroll
      for (int q = 0; q < 4; ++q) {
        int row = row0 + i * 16 + lq * 4 + q;
        int col = wn * 32 + j * 16 + lr;
        out[(size_t)row * C + col] = gelu_erf(acc[i][j][q]);
      }
}

extern "C" void kernel_launch(void* const* d_in, const int* in_sizes, int n_in,
                              void* d_out, int out_size, void* d_ws, size_t ws_size,
                              hipStream_t stream) {
  const float* x     = (const float*)d_in[0];
  const float* W_w   = (const float*)d_in[1];
  const float* W_b   = (const float*)d_in[2];
  const float* phi_w = (const float*)d_in[3];
  const float* phi_b = (const float*)d_in[4];
  const float* psi_w = (const float*)d_in[5];
  const float* psi_b = (const float*)d_in[6];
  float* out = (float*)d_out;

  // ws: partG[256*16384 bf16] | partS[256*128 f32] | gsumG[2*16384 f32]
  //     | gsumS[256 f32] | wtf[16384 bf16] | pwf[8192 bf16] | itf[16384 bf16]
  unsigned short* partG = (unsigned short*)d_ws;
  float* partS = (float*)(partG + (size_t)BATCH * NCHUNK * C * C);
  float* gsumG = partS + (size_t)BATCH * NCHUNK * C;
  float* gsumS = gsumG + BATCH * C * C;
  unsigned short* wtf = (unsigned short*)(gsumS + BATCH * C);
  unsigned short* pwf = wtf + 16384;
  unsigned short* itf = pwf + 8192;

  k_gram<<<BATCH * NCHUNK + 12, 512, 0, stream>>>(x, partG, partS, wtf, pwf, W_w, phi_w);
  k_reduce<<<(BATCH * C * C + BATCH * C + 511) / 512, 512, 0, stream>>>(partG, partS, gsumG, gsumS);
  k_integral<<<dim3(RANK, 4), 256, 0, stream>>>(psi_w, psi_b, gsumG, gsumS, itf);
  k_main<<<(BATCH * NB) / 32, 256, 0, stream>>>(x, W_b, phi_b, wtf, pwf, itf, out);
}

// Round 4
// 26.926 us; speedup vs baseline: 3.4700x; 1.0813x over previous
//
#include <hip/hip_runtime.h>
#include <hip/hip_bf16.h>
#include <math.h>

#define C 128
#define RANK 64
#define NB 8192
#define BATCH 2
#define NCHUNK 128                 // 64-row chunks per batch

typedef float f32x4 __attribute__((ext_vector_type(4)));
typedef short bf16x8 __attribute__((ext_vector_type(8)));
typedef unsigned short u16x4 __attribute__((ext_vector_type(4)));

__device__ __forceinline__ unsigned short f2b(float f) {
  __hip_bfloat16 h = __float2bfloat16(f);
  return *reinterpret_cast<unsigned short*>(&h);
}
__device__ __forceinline__ float b2f(unsigned short h) {
  union { unsigned u; float f; } v; v.u = ((unsigned)h) << 16;
  return v.f;
}
// cubic-tanh GELU, branch-free, |err| <= ~1e-3 vs exact erf form
__device__ __forceinline__ float gelu_fast(float y) {
  float u = y * (1.0f + 0.044715f * y * y);
  float e = __expf(1.5957691216057308f * u);     // e^{2*0.7978845608*u}
  float t = 1.0f - 2.0f / (e + 1.0f);            // tanh(0.79788456*u)
  return 0.5f * y * (1.0f + t);
}
#define MFMA(a, b, c) __builtin_amdgcn_mfma_f32_16x16x32_bf16(a, b, c, 0, 0, 0)

// ---------------------------------------------------------------------------
// k_gram: blocks [0,256): 64-row Gram partial via MFMA (8 waves), bf16 store,
// f32 column-sum partial. Blocks [256,268): pack W_w / phi_w to fragment order.
// Fragment order: o = ((nt*KT+kt)*64 + lane)*8 + j  holds
//   B[k = kt*32 + (lane>>4)*8 + j][n = nt*16 + (lane&15)].
// ---------------------------------------------------------------------------
__global__ __launch_bounds__(512) void k_gram(
    const float* __restrict__ x, unsigned short* __restrict__ partG,
    float* __restrict__ partS,
    unsigned short* __restrict__ wtf, unsigned short* __restrict__ pwf,
    const float* __restrict__ W_w, const float* __restrict__ phi_w) {
  const int blk = blockIdx.x;
  const int tid = threadIdx.x;
  if (blk >= BATCH * NCHUNK) {
    const int p = blk - BATCH * NCHUNK;
    if (p < 8) {   // W_w -> wtf, 16384 elems
      int o0 = p * 2048 + tid * 4;
      u16x4 v;
#pragma unroll
      for (int q = 0; q < 4; ++q) {
        int o = o0 + q;
        int j = o & 7, lane = (o >> 3) & 63, kt = (o >> 9) & 3, nt = o >> 11;
        int n = nt * 16 + (lane & 15);
        int k = kt * 32 + ((lane >> 4) << 3) + j;
        v[q] = f2b(W_w[k * C + n]);
      }
      *(u16x4*)(wtf + o0) = v;
    } else {       // phi_w -> pwf, 8192 elems
      int o0 = (p - 8) * 2048 + tid * 4;
      u16x4 v;
#pragma unroll
      for (int q = 0; q < 4; ++q) {
        int o = o0 + q;
        int j = o & 7, lane = (o >> 3) & 63, kt = (o >> 9) & 3, nt = o >> 11;
        int r = nt * 16 + (lane & 15);
        int c = kt * 32 + ((lane >> 4) << 3) + j;
        v[q] = f2b(phi_w[c * RANK + r]);
      }
      *(u16x4*)(pwf + o0) = v;
    }
    return;
  }
  __shared__ short xsT[C * 76];     // [c][n], stride 76: aligned + conflict-free
  __shared__ float csp[4][C];
  const int b = blk >> 7, chunk = blk & 127;
  const float* xb = x + ((size_t)(b * NB + chunk * 64)) * C;
  {
    const int c = tid & 127, ng = tid >> 7;   // ng 0..3
    float cs = 0.f;
#pragma unroll
    for (int it = 0; it < 4; ++it) {
      int n0 = it * 16 + ng * 4;
      u16x4 pv;
#pragma unroll
      for (int q = 0; q < 4; ++q) {
        float v = xb[(size_t)(n0 + q) * C + c];
        cs += v;
        pv[q] = f2b(v);
      }
      *(u16x4*)(&xsT[c * 76 + n0]) = pv;
    }
    csp[ng][c] = cs;
  }
  __syncthreads();
  const int l = tid & 63, w = tid >> 6;       // 8 waves, wave = row-tile
  const int lr = l & 15, lq = l >> 4;
  f32x4 acc[8];
#pragma unroll
  for (int tj = 0; tj < 8; ++tj) acc[tj] = (f32x4)(0.f);
  bf16x8 af[2];
#pragma unroll
  for (int kk = 0; kk < 2; ++kk)
    af[kk] = *(const bf16x8*)(&xsT[(w * 16 + lr) * 76 + kk * 32 + lq * 8]);
#pragma unroll
  for (int tj = 0; tj < 8; ++tj) {
#pragma unroll
    for (int kk = 0; kk < 2; ++kk) {
      bf16x8 bfr = *(const bf16x8*)(&xsT[(tj * 16 + lr) * 76 + kk * 32 + lq * 8]);
      acc[tj] = MFMA(af[kk], bfr, acc[tj]);
    }
  }
  unsigned short* dst = partG + (size_t)blk * (C * C);
#pragma unroll
  for (int tj = 0; tj < 8; ++tj)
#pragma unroll
    for (int q = 0; q < 4; ++q) {
      int ci = w * 16 + lq * 4 + q;
      int cj = tj * 16 + lr;
      dst[ci * C + cj] = f2b(acc[tj][q]);
    }
  if (tid < C)
    partS[blk * C + tid] = csp[0][tid] + csp[1][tid] + csp[2][tid] + csp[3][tid];
}

// ---------------------------------------------------------------------------
// k_reduce: chunk-parallel. Blocks [0,256): b = e>>7, i0 = (e&127)*128;
// 256 thr = (chg 8) x (ig 32); each thread sums 16 chunks of u16x4; LDS tree.
// Blocks [256,258): partS -> gsumS.
// ---------------------------------------------------------------------------
__global__ __launch_bounds__(256) void k_reduce(
    const unsigned short* __restrict__ partG, const float* __restrict__ partS,
    float* __restrict__ gsumG, float* __restrict__ gsumS) {
  const int e = blockIdx.x, tid = threadIdx.x;
  if (e < 256) {
    __shared__ f32x4 red[256];
    const int b = e >> 7, i0 = (e & 127) * 128;
    const int chg = tid >> 5, ig = tid & 31;
    f32x4 a = (f32x4)(0.f);
    const unsigned short* base =
        partG + (size_t)(b * NCHUNK + chg * 16) * (C * C) + i0 + ig * 4;
#pragma unroll
    for (int cc = 0; cc < 16; ++cc) {
      u16x4 v = *(const u16x4*)(base + (size_t)cc * (C * C));
#pragma unroll
      for (int q = 0; q < 4; ++q) a[q] += b2f(v[q]);
    }
    red[tid] = a;
    __syncthreads();
    if (tid < 32) {
      f32x4 s = red[tid];
#pragma unroll
      for (int g = 1; g < 8; ++g) {
        f32x4 r = red[g * 32 + tid];
#pragma unroll
        for (int q = 0; q < 4; ++q) s[q] += r[q];
      }
      *(f32x4*)(&gsumG[b * (C * C) + i0 + tid * 4]) = s;
    }
  } else {
    __shared__ float s2[2][C];
    const int b = e - 256;
    const int c = tid & 127, half = tid >> 7;
    const float* p = partS + (size_t)(b * NCHUNK + half * 64) * C + c;
    float s = 0.f;
#pragma unroll
    for (int cc = 0; cc < 64; ++cc) s += p[(size_t)cc * C];
    s2[half][c] = s;
    __syncthreads();
    if (tid < C) gsumS[b * C + tid] = s2[0][tid] + s2[1][tid];
  }
}

// ---------------------------------------------------------------------------
// k_integral: integ[b][r][c] = (sum_k psiw[k][r*C+c]*G[b][k][c]
//                               + psib[r*C+c]*S[b][c]) / NB -> itf (bf16 frag)
// grid (r=64, ch=4), 256 threads = kg(8) x c32(32); both batches per thread.
// ---------------------------------------------------------------------------
__global__ __launch_bounds__(256) void k_integral(
    const float* __restrict__ psi_w, const float* __restrict__ psi_b,
    const float* __restrict__ gsumG, const float* __restrict__ gsumS,
    unsigned short* __restrict__ itf) {
  __shared__ float red[2][8][32];
  const int r = blockIdx.x, ch = blockIdx.y;
  const int tid = threadIdx.x, kg = tid >> 5, c32 = tid & 31;
  const int c = ch * 32 + c32;
  const float* psW = psi_w + (size_t)r * C + c;
  const float* G0 = gsumG + c;
  const float* G1 = gsumG + C * C + c;
  float a0 = 0.f, a1 = 0.f;
#pragma unroll
  for (int i = 0; i < 16; ++i) {
    int k = kg * 16 + i;
    float pw = psW[(size_t)k * (RANK * C)];
    a0 += pw * G0[k * C];
    a1 += pw * G1[k * C];
  }
  red[0][kg][c32] = a0;
  red[1][kg][c32] = a1;
  __syncthreads();
  if (tid < 64) {
    int b = tid >> 5, cc = tid & 31;
    float s = 0.f;
#pragma unroll
    for (int g = 0; g < 8; ++g) s += red[b][g][cc];
    int cg = ch * 32 + cc;
    s += psi_b[r * C + cg] * gsumS[b * C + cg];
    s *= (1.0f / NB);
    int nt = cg >> 4, kt = r >> 5;
    int lane = ((r >> 3) & 3) * 16 + (cg & 15), j = r & 7;
    itf[(size_t)(((b * 8 + nt) * 2 + kt) * 64 + lane) * 8 + j] = f2b(s);
  }
}

// ---------------------------------------------------------------------------
// k_main: 32 rows/block, 256 threads (4 waves = 4 col-tiles), MFMA fused.
// A-fragments loaded DIRECTLY from row-major f32 x (L3-warm), converted
// in-register; no x LDS tile, single barrier (phi exchange).
//   T1 phi = x*phi_w + phi_b ; T2 acc = x*W_w + W_b ; T3 acc += phi*integ
//   out = gelu_fast(acc)
// ---------------------------------------------------------------------------
__global__ __launch_bounds__(256, 2) void k_main(
    const float* __restrict__ x, const float* __restrict__ W_b,
    const float* __restrict__ phi_b, const unsigned short* __restrict__ wtf,
    const unsigned short* __restrict__ pwf, const unsigned short* __restrict__ itf,
    float* __restrict__ out) {
  __shared__ short phT[32 * 72];
  const int tid = threadIdx.x, l = tid & 63, wn = tid >> 6;
  const int row0 = blockIdx.x * 32;
  const int b = blockIdx.x >> 8;
  const int lr = l & 15, lq = l >> 4;
  // weight fragments (coalesced 16B/lane)
  bf16x8 wb[2][4], pw[4], itb[2][2];
  const bf16x8* WF = (const bf16x8*)wtf;
  const bf16x8* PF = (const bf16x8*)pwf;
  const bf16x8* IF = (const bf16x8*)itf;
#pragma unroll
  for (int j = 0; j < 2; ++j)
#pragma unroll
    for (int kt = 0; kt < 4; ++kt)
      wb[j][kt] = WF[((wn * 2 + j) * 4 + kt) * 64 + l];
#pragma unroll
  for (int kt = 0; kt < 4; ++kt) pw[kt] = PF[(wn * 4 + kt) * 64 + l];
#pragma unroll
  for (int j = 0; j < 2; ++j)
#pragma unroll
    for (int kt = 0; kt < 2; ++kt)
      itb[j][kt] = IF[((b * 8 + wn * 2 + j) * 2 + kt) * 64 + l];
  // A-fragments straight from global x (f32 -> bf16 in-register)
  bf16x8 afr[2][4];
#pragma unroll
  for (int h = 0; h < 2; ++h) {
    const float* xr = x + (size_t)(row0 + h * 16 + lr) * C + lq * 8;
#pragma unroll
    for (int kt = 0; kt < 4; ++kt) {
      f32x4 v0 = *(const f32x4*)(xr + kt * 32);
      f32x4 v1 = *(const f32x4*)(xr + kt * 32 + 4);
      bf16x8 pv;
#pragma unroll
      for (int q = 0; q < 4; ++q) {
        pv[q] = (short)f2b(v0[q]);
        pv[q + 4] = (short)f2b(v1[q]);
      }
      afr[h][kt] = pv;
    }
  }
  float wb0 = W_b[wn * 32 + lr], wb1 = W_b[wn * 32 + 16 + lr];
  float pb0 = phi_b[wn * 16 + lr];
  f32x4 acc[2][2], pacc[2];
#pragma unroll
  for (int i = 0; i < 2; ++i) {
    acc[i][0] = (f32x4)(wb0);
    acc[i][1] = (f32x4)(wb1);
    pacc[i] = (f32x4)(pb0);
  }
#pragma unroll
  for (int kt = 0; kt < 4; ++kt) {
    pacc[0] = MFMA(afr[0][kt], pw[kt], pacc[0]);
    pacc[1] = MFMA(afr[1][kt], pw[kt], pacc[1]);
    acc[0][0] = MFMA(afr[0][kt], wb[0][kt], acc[0][0]);
    acc[0][1] = MFMA(afr[0][kt], wb[1][kt], acc[0][1]);
    acc[1][0] = MFMA(afr[1][kt], wb[0][kt], acc[1][0]);
    acc[1][1] = MFMA(afr[1][kt], wb[1][kt], acc[1][1]);
  }
#pragma unroll
  for (int i = 0; i < 2; ++i)
#pragma unroll
    for (int q = 0; q < 4; ++q) {
      int row = i * 16 + lq * 4 + q;
      phT[row * 72 + wn * 16 + lr] = (short)f2b(pacc[i][q]);
    }
  __syncthreads();
#pragma unroll
  for (int kt = 0; kt < 2; ++kt) {
    bf16x8 p0 = *(const bf16x8*)(&phT[lr * 72 + kt * 32 + lq * 8]);
    bf16x8 p1 = *(const bf16x8*)(&phT[(16 + lr) * 72 + kt * 32 + lq * 8]);
    acc[0][0] = MFMA(p0, itb[0][kt], acc[0][0]);
    acc[0][1] = MFMA(p0, itb[1][kt], acc[0][1]);
    acc[1][0] = MFMA(p1, itb[0][kt], acc[1][0]);
    acc[1][1] = MFMA(p1, itb[1][kt], acc[1][1]);
  }
#pragma unroll
  for (int i = 0; i < 2; ++i)
#pragma unroll
    for (int j = 0; j < 2; ++j)
#pragma unroll
      for (int q = 0; q < 4; ++q) {
        int row = row0 + i * 16 + lq * 4 + q;
        int col = wn * 32 + j * 16 + lr;
        out[(size_t)row * C + col] = gelu_fast(acc[i][j][q]);
      }
}

extern "C" void kernel_launch(void* const* d_in, const int* in_sizes, int n_in,
                              void* d_out, int out_size, void* d_ws, size_t ws_size,
                              hipStream_t stream) {
  const float* x     = (const float*)d_in[0];
  const float* W_w   = (const float*)d_in[1];
  const float* W_b   = (const float*)d_in[2];
  const float* phi_w = (const float*)d_in[3];
  const float* phi_b = (const float*)d_in[4];
  const float* psi_w = (const float*)d_in[5];
  const float* psi_b = (const float*)d_in[6];
  float* out = (float*)d_out;

  // ws: partG[256*16384 bf16] | partS[256*128 f32] | gsumG[2*16384 f32]
  //     | gsumS[256 f32] | wtf[16384 bf16] | pwf[8192 bf16] | itf[16384 bf16]
  unsigned short* partG = (unsigned short*)d_ws;
  float* partS = (float*)(partG + (size_t)BATCH * NCHUNK * C * C);
  float* gsumG = partS + (size_t)BATCH * NCHUNK * C;
  float* gsumS = gsumG + BATCH * C * C;
  unsigned short* wtf = (unsigned short*)(gsumS + BATCH * C);
  unsigned short* pwf = wtf + 16384;
  unsigned short* itf = pwf + 8192;

  k_gram<<<BATCH * NCHUNK + 12, 512, 0, stream>>>(x, partG, partS, wtf, pwf, W_w, phi_w);
  k_reduce<<<258, 256, 0, stream>>>(partG, partS, gsumG, gsumS);
  k_integral<<<dim3(RANK, 4), 256, 0, stream>>>(psi_w, psi_b, gsumG, gsumS, itf);
  k_main<<<(BATCH * NB) / 32, 256, 0, stream>>>(x, W_b, phi_b, wtf, pwf, itf, out);
}